// Round 7
// baseline (287.973 us; speedup 1.0000x reference)
//
#include <hip/hip_runtime.h>
#include <math.h>

#define NROW 16384
#define DIM 2048
#define NLAB 20
#define T_INV 10.0f
#define PD_EPS 1e-6f
#define NORM_EPS 1e-12f

#define BLOCKS 2048
#define THREADS 256
#define WPB (THREADS / 64)           // waves per block
#define TOTAL_WAVES (BLOCKS * WPB)
#define FRAG 8                       // float4 per lane: DIM/4/64 = 8

// ws layout (floats): [0]=sum_exp, [1]=sum_c, [2]=sum_c_ls, [3]=block counter (as uint)

__global__ __launch_bounds__(THREADS) void clloss_kernel(const float* __restrict__ embed,
                                                         const int* __restrict__ labels,
                                                         float* __restrict__ ws,
                                                         float* __restrict__ out) {
    const int tid = threadIdx.x;
    const int lane = tid & 63;
    const int wid = tid >> 6;

    // ---- prologue: build per-lane a-fragment (row 0 normalized + eps) in registers ----
    // Each wave's 64 lanes cover the full row, so a wave-local reduction gives the
    // complete row-0 norm; no cross-wave communication needed.
    const float4* row0 = (const float4*)embed;
    float4 v[FRAG];
#pragma unroll
    for (int it = 0; it < FRAG; ++it) v[it] = row0[it * 64 + lane];

    float s = 0.f;
#pragma unroll
    for (int it = 0; it < FRAG; ++it)
        s += v[it].x * v[it].x + v[it].y * v[it].y + v[it].z * v[it].z + v[it].w * v[it].w;
    for (int o = 32; o; o >>= 1) s += __shfl_xor(s, o, 64);
    const float inv0 = 1.0f / fmaxf(sqrtf(s), NORM_EPS);

    float4 av[FRAG];
    float saa = 0.f;
#pragma unroll
    for (int it = 0; it < FRAG; ++it) {
        av[it].x = v[it].x * inv0 + PD_EPS;
        av[it].y = v[it].y * inv0 + PD_EPS;
        av[it].z = v[it].z * inv0 + PD_EPS;
        av[it].w = v[it].w * inv0 + PD_EPS;
        saa += av[it].x * av[it].x + av[it].y * av[it].y +
               av[it].z * av[it].z + av[it].w * av[it].w;
    }
    for (int o = 32; o; o >>= 1) saa += __shfl_xor(saa, o, 64);
    const float S_aa = saa;  // identical across lanes

    const float lab0 = (lane < NLAB) ? (float)labels[lane] : 0.f;

    // ---- main loop: one row per wave per step, 2 steps total ----
    const int gw = blockIdx.x * WPB + wid;
    float acc_e = 0.f, acc_c = 0.f, acc_cl = 0.f;

    for (int row = 1 + gw; row < NROW; row += TOTAL_WAVES) {
        const float4* b4 = (const float4*)(embed + (size_t)row * DIM);
        float sab = 0.f, sbb = 0.f;
#pragma unroll
        for (int it = 0; it < FRAG; ++it) {
            float4 b = b4[it * 64 + lane];
            sab += av[it].x * b.x + av[it].y * b.y + av[it].z * b.z + av[it].w * b.w;
            sbb += b.x * b.x + b.y * b.y + b.z * b.z + b.w * b.w;
        }
        float c = (lane < NLAB) ? lab0 * (float)labels[row * NLAB + lane] : 0.f;

        for (int o = 32; o; o >>= 1) {
            sab += __shfl_xor(sab, o, 64);
            sbb += __shfl_xor(sbb, o, 64);
            c   += __shfl_xor(c,   o, 64);
        }
        // d^2 = S_aa - 2*(a.b)/||b|| + (b.b)/||b||^2
        float invb = 1.0f / fmaxf(sqrtf(sbb), NORM_EPS);
        float d2 = fmaxf(S_aa + invb * (invb * sbb - 2.0f * sab), 0.f);
        float ls = -sqrtf(d2) * T_INV;   // log_sim
        acc_e  += expf(ls);
        acc_c  += c;
        acc_cl += c * ls;
    }

    // ---- epilogue: block reduce -> device atomics -> last block finishes ----
    __shared__ float wsum[WPB][3];
    if (lane == 0) {
        wsum[wid][0] = acc_e;
        wsum[wid][1] = acc_c;
        wsum[wid][2] = acc_cl;
    }
    __syncthreads();
    if (tid == 0) {
        float se = 0.f, sc = 0.f, scl = 0.f;
        for (int w = 0; w < WPB; ++w) {
            se += wsum[w][0]; sc += wsum[w][1]; scl += wsum[w][2];
        }
        atomicAdd(&ws[0], se);
        atomicAdd(&ws[1], sc);
        atomicAdd(&ws[2], scl);
        __threadfence();
        unsigned prev = atomicAdd((unsigned*)&ws[3], 1u);
        if (prev == (unsigned)(BLOCKS - 1)) {
            // all other blocks' partial adds are globally visible (their fence
            // ordered partials before the counter bump). Read via atomic RMW
            // to stay coherent across XCDs.
            float Se  = atomicAdd(&ws[0], 0.f);
            float Sc  = atomicAdd(&ws[1], 0.f);
            float Scl = atomicAdd(&ws[2], 0.f);
            float Ci = 1e-12f + Sc;
            float Ei = 1e-12f + Se;
            float Li = (Sc * logf(Ei) - Scl) / Ci;
            out[0] = Li / (float)NROW;
        }
    }
}

extern "C" void kernel_launch(void* const* d_in, const int* in_sizes, int n_in,
                              void* d_out, int out_size, void* d_ws, size_t ws_size,
                              hipStream_t stream) {
    const float* embed = (const float*)d_in[0];
    const int* labels = (const int*)d_in[1];
    float* out = (float*)d_out;
    float* ws = (float*)d_ws;

    // zero the 3 accumulators + block counter (ws arrives poisoned with 0xAA)
    hipMemsetAsync(ws, 0, 16, stream);
    clloss_kernel<<<BLOCKS, THREADS, 0, stream>>>(embed, labels, ws, out);
}

// Round 8
// 194.737 us; speedup vs baseline: 1.4788x; 1.4788x over previous
//
#include <hip/hip_runtime.h>
#include <math.h>

#define NROW 16384
#define DIM 2048
#define NLAB 20
#define T_INV 10.0f
#define PD_EPS 1e-6f
#define NORM_EPS 1e-12f

#define BLOCKS 2048
#define THREADS 256
#define WPB (THREADS / 64)           // waves per block
#define TOTAL_WAVES (BLOCKS * WPB)
#define FRAG 8                       // float4 per lane: DIM/4/64 = 8

// ws layout: float4 per block: [blockIdx] = {sum_exp, sum_c, sum_c_ls, 0}
// No atomics, no zero-init needed: every slot is written every call.

__global__ __launch_bounds__(THREADS) void clloss_main(const float* __restrict__ embed,
                                                       const int* __restrict__ labels,
                                                       float4* __restrict__ partials) {
    const int tid = threadIdx.x;
    const int lane = tid & 63;
    const int wid = tid >> 6;

    // ---- prologue: per-lane a-fragment (row 0 normalized + eps) in registers ----
    const float4* row0 = (const float4*)embed;
    float4 v[FRAG];
#pragma unroll
    for (int it = 0; it < FRAG; ++it) v[it] = row0[it * 64 + lane];

    float s = 0.f;
#pragma unroll
    for (int it = 0; it < FRAG; ++it)
        s += v[it].x * v[it].x + v[it].y * v[it].y + v[it].z * v[it].z + v[it].w * v[it].w;
    for (int o = 32; o; o >>= 1) s += __shfl_xor(s, o, 64);
    const float inv0 = 1.0f / fmaxf(sqrtf(s), NORM_EPS);

    float4 av[FRAG];
    float saa = 0.f;
#pragma unroll
    for (int it = 0; it < FRAG; ++it) {
        av[it].x = v[it].x * inv0 + PD_EPS;
        av[it].y = v[it].y * inv0 + PD_EPS;
        av[it].z = v[it].z * inv0 + PD_EPS;
        av[it].w = v[it].w * inv0 + PD_EPS;
        saa += av[it].x * av[it].x + av[it].y * av[it].y +
               av[it].z * av[it].z + av[it].w * av[it].w;
    }
    for (int o = 32; o; o >>= 1) saa += __shfl_xor(saa, o, 64);
    const float S_aa = saa;

    const float lab0 = (lane < NLAB) ? (float)labels[lane] : 0.f;

    // ---- main loop: one row per wave per step ----
    const int gw = blockIdx.x * WPB + wid;
    float acc_e = 0.f, acc_c = 0.f, acc_cl = 0.f;

    for (int row = 1 + gw; row < NROW; row += TOTAL_WAVES) {
        const float4* b4 = (const float4*)(embed + (size_t)row * DIM);
        float sab = 0.f, sbb = 0.f;
#pragma unroll
        for (int it = 0; it < FRAG; ++it) {
            float4 b = b4[it * 64 + lane];
            sab += av[it].x * b.x + av[it].y * b.y + av[it].z * b.z + av[it].w * b.w;
            sbb += b.x * b.x + b.y * b.y + b.z * b.z + b.w * b.w;
        }
        float c = (lane < NLAB) ? lab0 * (float)labels[row * NLAB + lane] : 0.f;

        for (int o = 32; o; o >>= 1) {
            sab += __shfl_xor(sab, o, 64);
            sbb += __shfl_xor(sbb, o, 64);
            c   += __shfl_xor(c,   o, 64);
        }
        float invb = 1.0f / fmaxf(sqrtf(sbb), NORM_EPS);
        float d2 = fmaxf(S_aa + invb * (invb * sbb - 2.0f * sab), 0.f);
        float ls = -sqrtf(d2) * T_INV;
        acc_e  += expf(ls);
        acc_c  += c;
        acc_cl += c * ls;
    }

    // ---- epilogue: block partials to DISTINCT slots (no atomics) ----
    __shared__ float wsum[WPB][3];
    if (lane == 0) {
        wsum[wid][0] = acc_e;
        wsum[wid][1] = acc_c;
        wsum[wid][2] = acc_cl;
    }
    __syncthreads();
    if (tid == 0) {
        float4 p;
        p.x = wsum[0][0] + wsum[1][0] + wsum[2][0] + wsum[3][0];
        p.y = wsum[0][1] + wsum[1][1] + wsum[2][1] + wsum[3][1];
        p.z = wsum[0][2] + wsum[1][2] + wsum[2][2] + wsum[3][2];
        p.w = 0.f;
        partials[blockIdx.x] = p;
    }
}

// 1 block folds BLOCKS partials -> scalar.
__global__ __launch_bounds__(THREADS) void clloss_final(const float4* __restrict__ partials,
                                                        float* __restrict__ out) {
    __shared__ float red[THREADS / 64][3];
    const int tid = threadIdx.x;
    const int lane = tid & 63, wid = tid >> 6;

    float se = 0.f, sc = 0.f, scl = 0.f;
    for (int i = tid; i < BLOCKS; i += THREADS) {
        float4 p = partials[i];
        se += p.x; sc += p.y; scl += p.z;
    }
    for (int o = 32; o; o >>= 1) {
        se  += __shfl_xor(se,  o, 64);
        sc  += __shfl_xor(sc,  o, 64);
        scl += __shfl_xor(scl, o, 64);
    }
    if (lane == 0) { red[wid][0] = se; red[wid][1] = sc; red[wid][2] = scl; }
    __syncthreads();
    if (tid == 0) {
        se = sc = scl = 0.f;
        for (int w = 0; w < THREADS / 64; ++w) {
            se += red[w][0]; sc += red[w][1]; scl += red[w][2];
        }
        float Ci = 1e-12f + sc;
        float Ei = 1e-12f + se;
        float Li = (sc * logf(Ei) - scl) / Ci;
        out[0] = Li / (float)NROW;
    }
}

extern "C" void kernel_launch(void* const* d_in, const int* in_sizes, int n_in,
                              void* d_out, int out_size, void* d_ws, size_t ws_size,
                              hipStream_t stream) {
    const float* embed = (const float*)d_in[0];
    const int* labels = (const int*)d_in[1];
    float* out = (float*)d_out;
    float4* partials = (float4*)d_ws;

    clloss_main<<<BLOCKS, THREADS, 0, stream>>>(embed, labels, partials);
    clloss_final<<<1, THREADS, 0, stream>>>(partials, out);
}

// Round 11
// 191.124 us; speedup vs baseline: 1.5067x; 1.0189x over previous
//
#include <hip/hip_runtime.h>
#include <math.h>

#define NROW 16384
#define DIM 2048
#define NLAB 20
#define T_INV 10.0f
#define PD_EPS 1e-6f
#define NORM_EPS 1e-12f

#define BLOCKS 512
#define THREADS 256
#define WPB (THREADS / 64)            // 4 waves per block
#define TOTAL_WAVES (BLOCKS * WPB)    // 2048 -> 8 rows per wave
#define FRAG 8                        // float4 per lane: DIM/4/64 = 8

// ws: float4 partials[BLOCKS], each written unconditionally every call (no atomics).

__global__ __launch_bounds__(THREADS) void clloss_main(const float* __restrict__ embed,
                                                       const int* __restrict__ labels,
                                                       float4* __restrict__ partials) {
    const int tid = threadIdx.x;
    const int lane = tid & 63;
    const int wid = tid >> 6;

    // ---- prologue: a-fragment (row0 normalized + eps) in registers ----
    // Single combined reduce for s = sum(v^2) and sx = sum(v);
    // S_aa = inv^2*s + 2*eps*inv*sx + DIM*eps^2   (algebraic, no 2nd chain)
    const float4* row0 = (const float4*)embed;
    float4 a[FRAG];
#pragma unroll
    for (int it = 0; it < FRAG; ++it) a[it] = row0[it * 64 + lane];

    float s = 0.f, sx = 0.f;
#pragma unroll
    for (int it = 0; it < FRAG; ++it) {
        s  += a[it].x * a[it].x + a[it].y * a[it].y + a[it].z * a[it].z + a[it].w * a[it].w;
        sx += a[it].x + a[it].y + a[it].z + a[it].w;
    }
    for (int o = 32; o; o >>= 1) {
        s  += __shfl_xor(s,  o, 64);
        sx += __shfl_xor(sx, o, 64);
    }
    const float inv0 = 1.0f / fmaxf(sqrtf(s), NORM_EPS);
    const float S_aa = inv0 * inv0 * s + 2.0f * PD_EPS * inv0 * sx
                     + (float)DIM * PD_EPS * PD_EPS;
#pragma unroll
    for (int it = 0; it < FRAG; ++it) {
        a[it].x = a[it].x * inv0 + PD_EPS;
        a[it].y = a[it].y * inv0 + PD_EPS;
        a[it].z = a[it].z * inv0 + PD_EPS;
        a[it].w = a[it].w * inv0 + PD_EPS;
    }
    const float lab0 = (lane < NLAB) ? (float)labels[lane] : 0.f;

    // ---- main loop: 8 rows/wave, register double-buffered prefetch ----
    const int gw = blockIdx.x * WPB + wid;
    float acc_e = 0.f, acc_c = 0.f, acc_cl = 0.f;

    int row = 1 + gw;                 // gw <= 2047 < NROW, so always >= 1 row
    float4 cur[FRAG], nxt[FRAG];
    {
        const float4* p = (const float4*)(embed + (size_t)row * DIM);
#pragma unroll
        for (int it = 0; it < FRAG; ++it) cur[it] = p[it * 64 + lane];
    }

    while (row < NROW) {
        const int rnext = row + TOTAL_WAVES;
        const bool has_next = rnext < NROW;   // wave-uniform
        if (has_next) {
            const float4* q = (const float4*)(embed + (size_t)rnext * DIM);
#pragma unroll
            for (int it = 0; it < FRAG; ++it) nxt[it] = q[it * 64 + lane];
        }
        // label load hoisted ahead of the FMA block to hide latency
        float c = (lane < NLAB) ? lab0 * (float)labels[row * NLAB + lane] : 0.f;

        float sab = 0.f, sbb = 0.f;
#pragma unroll
        for (int it = 0; it < FRAG; ++it) {
            sab += a[it].x * cur[it].x + a[it].y * cur[it].y
                 + a[it].z * cur[it].z + a[it].w * cur[it].w;
            sbb += cur[it].x * cur[it].x + cur[it].y * cur[it].y
                 + cur[it].z * cur[it].z + cur[it].w * cur[it].w;
        }
        for (int o = 32; o; o >>= 1) {
            sab += __shfl_xor(sab, o, 64);
            sbb += __shfl_xor(sbb, o, 64);
            c   += __shfl_xor(c,   o, 64);
        }
        const float invb = 1.0f / fmaxf(sqrtf(sbb), NORM_EPS);
        const float d2 = fmaxf(S_aa + invb * (invb * sbb - 2.0f * sab), 0.f);
        const float ls = -sqrtf(d2) * T_INV;
        acc_e  += expf(ls);
        acc_c  += c;
        acc_cl += c * ls;

        if (has_next) {
#pragma unroll
            for (int it = 0; it < FRAG; ++it) cur[it] = nxt[it];
        }
        row = rnext;
    }

    // ---- epilogue: per-block partial to a distinct slot ----
    __shared__ float wsum[WPB][3];
    if (lane == 0) {
        wsum[wid][0] = acc_e;
        wsum[wid][1] = acc_c;
        wsum[wid][2] = acc_cl;
    }
    __syncthreads();
    if (tid == 0) {
        float4 p;
        p.x = wsum[0][0] + wsum[1][0] + wsum[2][0] + wsum[3][0];
        p.y = wsum[0][1] + wsum[1][1] + wsum[2][1] + wsum[3][1];
        p.z = wsum[0][2] + wsum[1][2] + wsum[2][2] + wsum[3][2];
        p.w = 0.f;
        partials[blockIdx.x] = p;
    }
}

// 1 block folds BLOCKS partials -> scalar.
__global__ __launch_bounds__(THREADS) void clloss_final(const float4* __restrict__ partials,
                                                        float* __restrict__ out) {
    __shared__ float red[THREADS / 64][3];
    const int tid = threadIdx.x;
    const int lane = tid & 63, wid = tid >> 6;

    float se = 0.f, sc = 0.f, scl = 0.f;
    for (int i = tid; i < BLOCKS; i += THREADS) {
        float4 p = partials[i];
        se += p.x; sc += p.y; scl += p.z;
    }
    for (int o = 32; o; o >>= 1) {
        se  += __shfl_xor(se,  o, 64);
        sc  += __shfl_xor(sc,  o, 64);
        scl += __shfl_xor(scl, o, 64);
    }
    if (lane == 0) { red[wid][0] = se; red[wid][1] = sc; red[wid][2] = scl; }
    __syncthreads();
    if (tid == 0) {
        se = sc = scl = 0.f;
        for (int w = 0; w < THREADS / 64; ++w) {
            se += red[w][0]; sc += red[w][1]; scl += red[w][2];
        }
        float Ci = 1e-12f + sc;
        float Ei = 1e-12f + se;
        float Li = (sc * logf(Ei) - scl) / Ci;
        out[0] = Li / (float)NROW;
    }
}

extern "C" void kernel_launch(void* const* d_in, const int* in_sizes, int n_in,
                              void* d_out, int out_size, void* d_ws, size_t ws_size,
                              hipStream_t stream) {
    const float* embed = (const float*)d_in[0];
    const int* labels = (const int*)d_in[1];
    float* out = (float*)d_out;
    float4* partials = (float4*)d_ws;

    clloss_main<<<BLOCKS, THREADS, 0, stream>>>(embed, labels, partials);
    clloss_final<<<1, THREADS, 0, stream>>>(partials, out);
}